// Round 5
// baseline (6325.520 us; speedup 1.0000x reference)
//
#include <hip/hip_runtime.h>
#include <hip/hip_bf16.h>
#include <stdint.h>

typedef unsigned short u16;

#define NB  32
#define NT  4096
#define NDZ 128
#define NG  384   // 3*DZ
#define NIN 192   // IN_DIM
#define CH  16    // scan chunk (steps staged per LDS refill)

// ---------- helpers ----------
__device__ __forceinline__ float rlane(float v, int k) {
  return __int_as_float(__builtin_amdgcn_readlane(__float_as_int(v), k));
}
__device__ __forceinline__ float fast_rcp(float x) { return __builtin_amdgcn_rcpf(x); }
__device__ __forceinline__ float sigmoid_f(float x) { return fast_rcp(1.f + __expf(-x)); }
__device__ __forceinline__ float tanh_f(float x) {
  return 1.f - 2.f * fast_rcp(1.f + __expf(2.f * x));
}
__device__ __forceinline__ u16 f2bf(float f) {
  unsigned u = __float_as_uint(f);
  return (u16)((u + 0x7fffu + ((u >> 16) & 1u)) >> 16);
}
__device__ __forceinline__ void unpack8(uint4 v, float* f) {
  f[0] = __uint_as_float(v.x << 16); f[1] = __uint_as_float(v.x & 0xffff0000u);
  f[2] = __uint_as_float(v.y << 16); f[3] = __uint_as_float(v.y & 0xffff0000u);
  f[4] = __uint_as_float(v.z << 16); f[5] = __uint_as_float(v.z & 0xffff0000u);
  f[6] = __uint_as_float(v.w << 16); f[7] = __uint_as_float(v.w & 0xffff0000u);
}
__device__ __forceinline__ void store8(u16* p, const float* v) {
  uint4 o;
  o.x = (unsigned)f2bf(v[0]) | ((unsigned)f2bf(v[1]) << 16);
  o.y = (unsigned)f2bf(v[2]) | ((unsigned)f2bf(v[3]) << 16);
  o.z = (unsigned)f2bf(v[4]) | ((unsigned)f2bf(v[5]) << 16);
  o.w = (unsigned)f2bf(v[6]) | ((unsigned)f2bf(v[7]) << 16);
  *(uint4*)p = o;
}

// ---------- Phase 1: gi = x @ W_ih^T + b_ih -> bf16 (validated R3/R4) ----------
#define GM 128
#define GN 128
#define LDSS 132

__global__ __launch_bounds__(256) void gemm_gi(
    const float* __restrict__ Y, const float* __restrict__ M,
    const float* __restrict__ H, const float* __restrict__ Wih,
    const float* __restrict__ bih, u16* __restrict__ gi)
{
  __shared__ float As[32 * LDSS];
  __shared__ float Bs[32 * LDSS];
  const int tid = threadIdx.x;
  const size_t m0 = (size_t)blockIdx.x * GM;
  const int n0 = blockIdx.y * GN;
  const int tm = tid & 15;
  const int tn = tid >> 4;

  float acc[8][8];
#pragma unroll
  for (int i = 0; i < 8; ++i)
#pragma unroll
    for (int j = 0; j < 8; ++j) acc[i][j] = 0.f;

#pragma unroll
  for (int kc = 0; kc < 6; ++kc) {
    const float* src; int stride; int off;
    if (kc == 0)      { src = Y; stride = 32;  off = 0; }
    else if (kc == 1) { src = M; stride = 32;  off = 0; }
    else              { src = H; stride = 128; off = (kc - 2) * 32; }
#pragma unroll
    for (int it = 0; it < 4; ++it) {
      int x = tid + it * 256;
      int row = x >> 3, q = x & 7;
      float4 v = *(const float4*)(src + (m0 + (size_t)row) * stride + off + q * 4);
      As[(q * 4 + 0) * LDSS + row] = v.x;
      As[(q * 4 + 1) * LDSS + row] = v.y;
      As[(q * 4 + 2) * LDSS + row] = v.z;
      As[(q * 4 + 3) * LDSS + row] = v.w;
    }
#pragma unroll
    for (int it = 0; it < 4; ++it) {
      int x = tid + it * 256;
      int g = x >> 3, q = x & 7;
      float4 v = *(const float4*)(Wih + (size_t)(n0 + g) * NIN + kc * 32 + q * 4);
      Bs[(q * 4 + 0) * LDSS + g] = v.x;
      Bs[(q * 4 + 1) * LDSS + g] = v.y;
      Bs[(q * 4 + 2) * LDSS + g] = v.z;
      Bs[(q * 4 + 3) * LDSS + g] = v.w;
    }
    __syncthreads();
#pragma unroll
    for (int kk = 0; kk < 32; ++kk) {
      float4 a0 = *(const float4*)&As[kk * LDSS + tm * 8];
      float4 a1 = *(const float4*)&As[kk * LDSS + tm * 8 + 4];
      float4 b0 = *(const float4*)&Bs[kk * LDSS + tn * 8];
      float4 b1 = *(const float4*)&Bs[kk * LDSS + tn * 8 + 4];
      float av[8] = {a0.x, a0.y, a0.z, a0.w, a1.x, a1.y, a1.z, a1.w};
      float bv[8] = {b0.x, b0.y, b0.z, b0.w, b1.x, b1.y, b1.z, b1.w};
#pragma unroll
      for (int i = 0; i < 8; ++i)
#pragma unroll
        for (int j = 0; j < 8; ++j)
          acc[i][j] = __builtin_fmaf(av[i], bv[j], acc[i][j]);
    }
    __syncthreads();
  }
  float bv[8];
#pragma unroll
  for (int j = 0; j < 8; ++j) bv[j] = bih[n0 + tn * 8 + j];
#pragma unroll
  for (int i = 0; i < 8; ++i) {
    size_t row = m0 + (size_t)(tm * 8 + i);
    u16* o = gi + row * NG + n0 + tn * 8;
    float v[8];
#pragma unroll
    for (int j = 0; j < 8; ++j) v[j] = acc[i][j] + bv[j];
    store8(o, v);
  }
}

// ---------- Phase 2: scan, 512 thr, chunked LDS staging (no VMEM in loop) ----
// Wave w owns k-slice [16w,16w+16); lane holds 6 rows x 16 k = 96 weight VGPRs.
// Step: [gate: zd->zbuf] B1 [all: matvec->P] B2 [gate: reduce+gates, traj->LDS]
// Chunk top: stage next gi/t chunk + flush prev traj chunk -> vmcnt drain at
// the barrier happens once per CH steps, not every step (R4's 2800cyc/step bug).
// Tail (t>=len): closed-form decay, fully parallel, no barriers.
__global__ __launch_bounds__(512, 2) void scan_k(
    const float* __restrict__ zinit, const float* __restrict__ tdyn,
    const int* __restrict__ lens, const float* __restrict__ Whh,
    const float* __restrict__ bhh, const float* __restrict__ lgam,
    const u16* __restrict__ gi, float* __restrict__ out)
{
  const int b = blockIdx.x;
  const int tid = threadIdx.x;   // 0..511
  const int lane = tid & 63;
  const int w = tid >> 6;        // wave 0..7
  const int k0 = w * 16;

  __shared__ float gis[2][CH * NG];   // 48 KB staged gi (f32, unpacked)
  __shared__ float tbuf[2][CH];       // staged t
  __shared__ float P[8][NG];          // 12 KB matvec partials
  __shared__ float zbuf[NDZ];
  __shared__ float trajb[CH * NDZ];   // 8 KB traj chunk buffer
  __shared__ float gbuf[NDZ];
  __shared__ float tstar_sh;

  // weights: row pairs (lane+128p, lane+128p+64), k in [k0,k0+16)
  float2 wp[3][16];
#pragma unroll
  for (int p = 0; p < 3; ++p) {
    const float* r0 = Whh + (size_t)(lane + 128 * p) * NDZ + k0;
    const float* r1 = Whh + (size_t)(lane + 128 * p + 64) * NDZ + k0;
    float4 a[4], c[4];
#pragma unroll
    for (int q = 0; q < 4; ++q) { a[q] = ((const float4*)r0)[q]; c[q] = ((const float4*)r1)[q]; }
    const float* af = (const float*)a;
    const float* cf = (const float*)c;
#pragma unroll
    for (int k = 0; k < 16; ++k) { wp[p][k].x = af[k]; wp[p][k].y = cf[k]; }
  }

  const int len = lens[b];
  const bool gate = (tid < NDZ);
  const int j = tid;

  const float* tp = tdyn + (size_t)b * NT;
  const u16* gb = gi + (size_t)b * NT * NG;
  float* traj = out + (size_t)NB * NDZ + (size_t)b * NT * NDZ;

  float zc = 0.f, zd = 0.f, gam = 0.f, br = 0.f, bu = 0.f, bn = 0.f, t_prev = 0.f;
  if (gate) {
    zc = zinit[b * NDZ + j];
    const float lg = lgam[j];
    gam = (lg > 15.f) ? lg : __logf(1.f + __expf(lg));
    br = bhh[j]; bu = bhh[NDZ + j]; bn = bhh[2 * NDZ + j];
    t_prev = tp[0];
  }

  // stage chunk (gi bf16 -> f32 LDS, + t values); CH*NG/8 = 768 uint4 loads
  auto stage = [&](int t0s, int bufi) {
    const u16* src = gb + (size_t)t0s * NG;
    for (int i = tid; i < (CH * NG) / 8; i += 512) {
      uint4 v = *(const uint4*)(src + 8 * i);
      float f[8]; unpack8(v, f);
      float4 lo = {f[0], f[1], f[2], f[3]}, hi = {f[4], f[5], f[6], f[7]};
      *(float4*)&gis[bufi][8 * i] = lo;
      *(float4*)&gis[bufi][8 * i + 4] = hi;
    }
    if (tid < CH) tbuf[bufi][tid] = tp[t0s + tid];
  };

  stage(0, 0);
  int t0 = 0, last_t0 = 0, prev_t0 = -1;
  while (t0 < len) {
    last_t0 = t0;
    const int bufi = (t0 >> 4) & 1;
    const int tend = (t0 + CH < len) ? t0 + CH : len;
    __syncthreads();  // publish staged chunk + prev-chunk trajb
    const int tn0 = t0 + CH;
    if (tn0 < len) stage(tn0, bufi ^ 1);
    if (prev_t0 >= 0) {  // flush previous (always full) chunk
      float4 v = *(float4*)&trajb[tid * 4];
      *(float4*)(traj + (size_t)prev_t0 * NDZ + tid * 4) = v;
    }
    for (int t = t0; t < tend; ++t) {
      const int ts = t - t0;
      if (gate) {
        const float tk = tbuf[bufi][ts];
        const float dt = fmaxf(tk - t_prev, 0.f);
        zd = zc * __expf(-gam * dt);
        zbuf[j] = zd;
        t_prev = tk;
      }
      __syncthreads();  // B1: zbuf published
      {
        const float vz = zbuf[k0 + (lane & 15)];
        float2 a0 = {0.f, 0.f}, a1 = {0.f, 0.f}, a2 = {0.f, 0.f};
#pragma unroll
        for (int k = 0; k < 16; ++k) {
          const float zk = rlane(vz, k);
          a0.x = __builtin_fmaf(wp[0][k].x, zk, a0.x);
          a0.y = __builtin_fmaf(wp[0][k].y, zk, a0.y);
          a1.x = __builtin_fmaf(wp[1][k].x, zk, a1.x);
          a1.y = __builtin_fmaf(wp[1][k].y, zk, a1.y);
          a2.x = __builtin_fmaf(wp[2][k].x, zk, a2.x);
          a2.y = __builtin_fmaf(wp[2][k].y, zk, a2.y);
        }
        P[w][lane]       = a0.x;  P[w][lane + 64]  = a0.y;
        P[w][lane + 128] = a1.x;  P[w][lane + 192] = a1.y;
        P[w][lane + 256] = a2.x;  P[w][lane + 320] = a2.y;
      }
      __syncthreads();  // B2: partials published
      if (gate) {
        const float sr = ((P[0][j] + P[1][j]) + (P[2][j] + P[3][j]))
                       + ((P[4][j] + P[5][j]) + (P[6][j] + P[7][j]));
        const float su = ((P[0][NDZ + j] + P[1][NDZ + j]) + (P[2][NDZ + j] + P[3][NDZ + j]))
                       + ((P[4][NDZ + j] + P[5][NDZ + j]) + (P[6][NDZ + j] + P[7][NDZ + j]));
        const float sn = ((P[0][2 * NDZ + j] + P[1][2 * NDZ + j]) + (P[2][2 * NDZ + j] + P[3][2 * NDZ + j]))
                       + ((P[4][2 * NDZ + j] + P[5][2 * NDZ + j]) + (P[6][2 * NDZ + j] + P[7][2 * NDZ + j]));
        const float* gc = &gis[bufi][ts * NG];
        const float r = sigmoid_f(sr + br + gc[j]);
        const float u = sigmoid_f(su + bu + gc[NDZ + j]);
        const float n = tanh_f(__builtin_fmaf(r, sn + bn, gc[2 * NDZ + j]));
        zc = (1.f - u) * n + u * zd;
        trajb[ts * NDZ + j] = zc;
      }
    }
    prev_t0 = t0;
    t0 = tend;
  }

  // final flush of last (possibly partial) chunk
  __syncthreads();
  {
    const int nfl = (len - last_t0) * NDZ;
    if (tid * 4 < nfl) {
      float4 v = *(float4*)&trajb[tid * 4];
      *(float4*)(traj + (size_t)last_t0 * NDZ + tid * 4) = v;
    }
  }

  // closed-form decay tail: traj[t] = z* . exp(-gamma (t_t - t*)), t in [len,NT)
  if (gate) { zbuf[j] = zc; gbuf[j] = gam; }
  if (tid == 0) tstar_sh = t_prev;
  __syncthreads();
  const float tst = tstar_sh;
  const int j2 = tid & 127;
  const float zs = zbuf[j2], gs = gbuf[j2];
  for (int t = len + (tid >> 7); t < NT; t += 4) {
    const float tk = tp[t];
    traj[(size_t)t * NDZ + j2] = zs * __expf(-gs * (tk - tst));
  }
  if (gate) {
    const float zf = (len == NT) ? zc : zs * __expf(-gs * (tp[NT - 1] - tst));
    out[b * NDZ + j] = zf;
  }
}

extern "C" void kernel_launch(void* const* d_in, const int* in_sizes, int n_in,
                              void* d_out, int out_size, void* d_ws, size_t ws_size,
                              hipStream_t stream) {
  const float* z0   = (const float*)d_in[0];
  const float* tdyn = (const float*)d_in[1];
  const float* Y    = (const float*)d_in[2];
  const float* M    = (const float*)d_in[3];
  const int*   lens = (const int*)d_in[4];
  const float* H    = (const float*)d_in[5];
  const float* Wih  = (const float*)d_in[6];
  const float* bih  = (const float*)d_in[7];
  const float* Whh  = (const float*)d_in[8];
  const float* bhh  = (const float*)d_in[9];
  const float* lgam = (const float*)d_in[10];
  float* out = (float*)d_out;  // f32: [B*DZ] z_final, then [B*T*DZ] Z_traj

  u16* gi = (u16*)d_ws;  // bf16 gi, 100.7 MB (validated: R3/R4 absmax 3.9e-3)
  gemm_gi<<<dim3((NB * NT) / GM, NG / GN), 256, 0, stream>>>(Y, M, H, Wih, bih, gi);
  scan_k<<<dim3(NB), 512, 0, stream>>>(z0, tdyn, lens, Whh, bhh, lgam, gi, out);
}